// Round 1
// baseline (1435.634 us; speedup 1.0000x reference)
//
#include <hip/hip_runtime.h>
#include <hip/hip_bf16.h>
#include <stdint.h>

typedef short short8 __attribute__((ext_vector_type(8)));
typedef short short4v __attribute__((ext_vector_type(4)));
typedef float f32x4 __attribute__((ext_vector_type(4)));

static __device__ __forceinline__ short f2bf(float f) {
  union { float f; uint32_t u; } v; v.f = f;
  uint32_t r = (v.u + 0x7fffu + ((v.u >> 16) & 1u)) >> 16;
  return (short)(uint16_t)r;
}
static __device__ __forceinline__ float bf2f(short h) {
  union { uint32_t u; float f; } v; v.u = ((uint32_t)(uint16_t)h) << 16;
  return v.f;
}

#define MFMA(a, b, c) __builtin_amdgcn_mfma_f32_16x16x32_bf16((a), (b), (c), 0, 0, 0)

// ---------------------------------------------------------------------------
// Kernel 1: QKV projection GEMM.  x[16384][1024] f32, W[1024][1024] f32.
//   z=0 -> Q bf16 [16384][1024], pre-scaled by 1/32
//   z=1 -> K bf16 [16384][1024]
//   z=2 -> V^T bf16 [4][1024][4096]   (d-major, so PV B-frags are contiguous)
// 128x128 tile, 4 waves (each 64x64), K-step 32.
// ---------------------------------------------------------------------------
__global__ __launch_bounds__(256)
void qkv_gemm(const float* __restrict__ x,
              const float* __restrict__ Wq, const float* __restrict__ Wk,
              const float* __restrict__ Wv,
              short* __restrict__ q_out, short* __restrict__ k_out,
              short* __restrict__ vt_out)
{
  __shared__ short Alds[128][40];   // [m][k] +8 pad (80B rows, 16B aligned)
  __shared__ short Blds[128][40];   // [n][k] +8 pad (W transposed on store)

  const int z  = blockIdx.z;
  const float* W = (z == 0) ? Wq : (z == 1) ? Wk : Wv;
  const int m0 = blockIdx.y * 128;
  const int n0 = blockIdx.x * 128;
  const int t  = threadIdx.x;
  const int w  = t >> 6, lane = t & 63;
  const int wr = (w >> 1) * 64, wc = (w & 1) * 64;
  const int lr = lane & 15, lk = lane >> 4;

  f32x4 acc[4][4] = {};

  for (int k0 = 0; k0 < 1024; k0 += 32) {
    if (k0) __syncthreads();             // protect LDS from previous compute
    // stage A: 128 rows x 32 k, f32 -> bf16
#pragma unroll
    for (int j = 0; j < 4; ++j) {
      int fid = j * 256 + t;             // 1024 float4s
      int row = fid >> 3, c4 = fid & 7;
      f32x4 a = *(const f32x4*)(x + (size_t)(m0 + row) * 1024 + k0 + c4 * 4);
      short4v h = { f2bf(a.x), f2bf(a.y), f2bf(a.z), f2bf(a.w) };
      *(short4v*)&Alds[row][c4 * 4] = h;
    }
    // stage B: W rows k0..k0+32, cols n0..n0+128, transpose into [n][k]
#pragma unroll
    for (int j = 0; j < 4; ++j) {
      int fid = j * 256 + t;             // 1024 float4s
      int krow = fid >> 5, n4 = fid & 31;
      f32x4 bv = *(const f32x4*)(W + (size_t)(k0 + krow) * 1024 + n0 + n4 * 4);
      Blds[n4 * 4 + 0][krow] = f2bf(bv.x);
      Blds[n4 * 4 + 1][krow] = f2bf(bv.y);
      Blds[n4 * 4 + 2][krow] = f2bf(bv.z);
      Blds[n4 * 4 + 3][krow] = f2bf(bv.w);
    }
    __syncthreads();

    short8 af[4], bf[4];
#pragma unroll
    for (int mt = 0; mt < 4; ++mt)
      af[mt] = *(const short8*)&Alds[wr + mt * 16 + lr][lk * 8];
#pragma unroll
    for (int nt = 0; nt < 4; ++nt)
      bf[nt] = *(const short8*)&Blds[wc + nt * 16 + lr][lk * 8];
#pragma unroll
    for (int mt = 0; mt < 4; ++mt)
#pragma unroll
      for (int nt = 0; nt < 4; ++nt)
        acc[mt][nt] = MFMA(af[mt], bf[nt], acc[mt][nt]);
  }

  // epilogue: C/D layout col = lane&15, row = (lane>>4)*4 + i
#pragma unroll
  for (int mt = 0; mt < 4; ++mt) {
#pragma unroll
    for (int nt = 0; nt < 4; ++nt) {
      int col = n0 + wc + nt * 16 + lr;
      int rbase = m0 + wr + mt * 16 + lk * 4;
      if (z == 2) {
        int b = rbase >> 12, s = rbase & 4095;   // 4 consecutive s, same batch
        short4v h = { f2bf(acc[mt][nt][0]), f2bf(acc[mt][nt][1]),
                      f2bf(acc[mt][nt][2]), f2bf(acc[mt][nt][3]) };
        *(short4v*)(vt_out + ((size_t)b * 1024 + col) * 4096 + s) = h;
      } else {
        short* dst = (z == 0) ? q_out : k_out;
        float scale = (z == 0) ? 0.03125f : 1.0f;
#pragma unroll
        for (int i = 0; i < 4; ++i)
          dst[(size_t)(rbase + i) * 1024 + col] = f2bf(acc[mt][nt][i] * scale);
      }
    }
  }
}

// ---------------------------------------------------------------------------
// Kernel 2: causal flash attention.  Q pre-scaled.  8 waves / block.
// Q-block = 16 rows (staged in LDS).  KV-tile = 128 (wave w owns 16 kv cols
// for QK^T and d-chunk [w*128, w*128+128) for PV).
// ---------------------------------------------------------------------------
__global__ __launch_bounds__(512)
void attn_kernel(const short* __restrict__ Q, const short* __restrict__ K,
                 const short* __restrict__ VT, float* __restrict__ out)
{
  __shared__ short Qlds[16][1032];   // +8 pad; 2064B rows (16B aligned)
  __shared__ short Plds[16][136];    // +8 pad; 272B rows
  __shared__ float smax[8][16];
  __shared__ float ssum[8][16];

  const int bi = blockIdx.x;
  const int b  = bi & 3;
  const int qt = 255 - (bi >> 2);    // reverse order: biggest causal extent first
  const int q0 = qt * 16;
  const int t  = threadIdx.x;
  const int w  = t >> 6, lane = t & 63;
  const int lr = lane & 15, lk = lane >> 4;

  // stage Q tile (16 x 1024 bf16 = 32KB), coalesced 16B chunks
#pragma unroll
  for (int j = 0; j < 4; ++j) {
    int c = j * 512 + t;                 // 2048 chunks of 8 bf16
    int row = c >> 7, c8 = c & 127;
    *(short8*)&Qlds[row][c8 * 8] =
        *(const short8*)(Q + ((size_t)(b * 4096 + q0 + row)) * 1024 + c8 * 8);
  }
  __syncthreads();

  float m_i[4], l_i[4];
#pragma unroll
  for (int i = 0; i < 4; ++i) { m_i[i] = -1e30f; l_i[i] = 0.f; }
  f32x4 o[8] = {};

  const int ntiles = (q0 + 16 + 127) >> 7;
  for (int tile = 0; tile < ntiles; ++tile) {
    const int kv0 = tile << 7;

    // ---- QK^T: S[16 rows x 16 cols] for this wave ----
    f32x4 s = {};
    {
      const short* kp = K + ((size_t)(b * 4096 + kv0 + w * 16 + lr)) * 1024 + lk * 8;
#pragma unroll
      for (int ks = 0; ks < 32; ++ks) {
        short8 a  = *(const short8*)&Qlds[lr][ks * 32 + lk * 8];
        short8 bb = *(const short8*)(kp + ks * 32);
        s = MFMA(a, bb, s);
      }
    }
    // causal mask (col > row -> -1e30)
#pragma unroll
    for (int i = 0; i < 4; ++i) {
      int row = q0 + lk * 4 + i;
      int col = kv0 + w * 16 + lr;
      if (col > row) s[i] = -1e30f;
    }
    // wave-local row max (reduce across the 16 lanes of each lane-group)
    float pm[4];
#pragma unroll
    for (int i = 0; i < 4; ++i) {
      float v = s[i];
      v = fmaxf(v, __shfl_xor(v, 1));
      v = fmaxf(v, __shfl_xor(v, 2));
      v = fmaxf(v, __shfl_xor(v, 4));
      v = fmaxf(v, __shfl_xor(v, 8));
      pm[i] = v;
    }
    if (lr == 0) {
#pragma unroll
      for (int i = 0; i < 4; ++i) smax[w][lk * 4 + i] = pm[i];
    }
    __syncthreads();

    float mnew[4];
#pragma unroll
    for (int i = 0; i < 4; ++i) {
      float v = m_i[i];
#pragma unroll
      for (int w2 = 0; w2 < 8; ++w2) v = fmaxf(v, smax[w2][lk * 4 + i]);
      mnew[i] = v;
    }

    // P = exp(S - mnew); store bf16 P; partial row sums of the ROUNDED P
    float psum[4];
#pragma unroll
    for (int i = 0; i < 4; ++i) {
      float p = __expf(s[i] - mnew[i]);
      short pb = f2bf(p);
      Plds[lk * 4 + i][w * 16 + lr] = pb;
      float v = bf2f(pb);                 // sum the quantized value (no bias)
      v += __shfl_xor(v, 1);
      v += __shfl_xor(v, 2);
      v += __shfl_xor(v, 4);
      v += __shfl_xor(v, 8);
      psum[i] = v;
    }
    if (lr == 0) {
#pragma unroll
      for (int i = 0; i < 4; ++i) ssum[w][lk * 4 + i] = psum[i];
    }
    __syncthreads();

    // update running stats, rescale O
#pragma unroll
    for (int i = 0; i < 4; ++i) {
      float ts = 0.f;
#pragma unroll
      for (int w2 = 0; w2 < 8; ++w2) ts += ssum[w2][lk * 4 + i];
      float sc = __expf(m_i[i] - mnew[i]);
      l_i[i] = l_i[i] * sc + ts;
      m_i[i] = mnew[i];
#pragma unroll
      for (int dt = 0; dt < 8; ++dt) o[dt][i] *= sc;
    }

    // ---- PV: O[16 x 128(d-chunk)] += P[16 x 128(kv)] * V[kv x d] ----
    short8 pa[4];
#pragma unroll
    for (int ks = 0; ks < 4; ++ks)
      pa[ks] = *(const short8*)&Plds[lr][ks * 32 + lk * 8];
#pragma unroll
    for (int dt = 0; dt < 8; ++dt) {
      const short* vp =
          VT + ((size_t)b * 1024 + w * 128 + dt * 16 + lr) * 4096 + kv0 + lk * 8;
#pragma unroll
      for (int ks = 0; ks < 4; ++ks) {
        short8 bb = *(const short8*)(vp + ks * 32);
        o[dt] = MFMA(pa[ks], bb, o[dt]);
      }
    }
    __syncthreads();   // protect Plds/smax/ssum for next tile
  }

  // epilogue: out = O / l, fp32
#pragma unroll
  for (int dt = 0; dt < 8; ++dt) {
#pragma unroll
    for (int i = 0; i < 4; ++i) {
      int row = q0 + lk * 4 + i;
      int col = w * 128 + dt * 16 + lr;
      out[((size_t)(b * 4096 + row)) * 1024 + col] = o[dt][i] / l_i[i];
    }
  }
}

// ---------------------------------------------------------------------------
extern "C" void kernel_launch(void* const* d_in, const int* in_sizes, int n_in,
                              void* d_out, int out_size, void* d_ws, size_t ws_size,
                              hipStream_t stream) {
  (void)in_sizes; (void)n_in; (void)out_size; (void)ws_size;
  const float* x  = (const float*)d_in[0];
  const float* Wq = (const float*)d_in[1];
  const float* Wk = (const float*)d_in[2];
  const float* Wv = (const float*)d_in[3];
  float* out = (float*)d_out;

  short* q_ws  = (short*)d_ws;                       // 16384*1024 bf16
  short* k_ws  = q_ws + (size_t)16384 * 1024;        // 16384*1024 bf16
  short* vt_ws = k_ws + (size_t)16384 * 1024;        // 4*1024*4096 bf16

  dim3 g1(8, 128, 3);
  qkv_gemm<<<g1, 256, 0, stream>>>(x, Wq, Wk, Wv, q_ws, k_ws, vt_ws);
  attn_kernel<<<dim3(1024), 512, 0, stream>>>(q_ws, k_ws, vt_ws, out);
}